// Round 3
// baseline (149.020 us; speedup 1.0000x reference)
//
#include <hip/hip_runtime.h>

// Problem shape (fixed by reference setup_inputs)
constexpr int F = 2, B = 64, S = 512, D = 768;
constexpr int NCHUNK = 32;            // S-chunks per (f,b)
constexpr int SROWS = S / NCHUNK;     // 16 rows per block
constexpr int TPB = D / 4;            // 192 threads, one float4 column slice each
constexpr int NBLK = F * B * NCHUNK;  // 4096 blocks (1.5x oversubscribed -> tail smoothing)
constexpr float EPS = 1e-9f;

// Single fused kernel:
//   per-block: partial T contribution for (fb, chunk) -> ws[blk]
//   last-arriving block (device-scope acq_rel counter): T/(T+eps) per fb, sum, out[0].
__global__ __launch_bounds__(TPB) void nl_fused(
        const float* __restrict__ tok,   // [F*B, S, D]
        const float* __restrict__ sent,  // [F*B, D]
        const int*   __restrict__ mask,  // [F*B, S]
        float* __restrict__ ws,          // [NBLK] partials
        int*   __restrict__ cnt,         // zeroed by memset node each call
        float* __restrict__ out)
{
    const int blk   = blockIdx.x;            // fb*NCHUNK + chunk
    const int fb    = blk / NCHUNK;
    const int chunk = blk - fb * NCHUNK;
    const int tid   = threadIdx.x;
    const int lane  = tid & 63;

    __shared__ int idxs[SROWS];
    __shared__ int nact;
    __shared__ float sm[TPB / 64];
    __shared__ int is_last;

    const float4 sv = reinterpret_cast<const float4*>(sent + (size_t)fb * D)[tid];

    // active-row list (mask != 0), built by wave 0
    const int* mrow = mask + (size_t)fb * S + chunk * SROWS;
    int mv = 0;
    if (lane < SROWS) mv = mrow[lane];
    unsigned long long bal = __ballot(mv != 0);
    if (tid < 64) {
        if (mv != 0) {
            int pos = __popcll(bal & ((1ull << lane) - 1ull));
            idxs[pos] = lane;
        }
        if (lane == 0) nact = __popcll(bal);
    }
    __syncthreads();
    const int n = nact;

    // dense masked column accumulation
    const float* tbase = tok + (size_t)fb * S * D + (size_t)chunk * SROWS * D;
    float4 acc = make_float4(0.f, 0.f, 0.f, 0.f);
#pragma unroll 4
    for (int j = 0; j < n; ++j) {
        const int s = idxs[j];
        float4 t = reinterpret_cast<const float4*>(tbase + (size_t)s * D)[tid];
        acc.x += t.x; acc.y += t.y; acc.z += t.z; acc.w += t.w;
    }
    float p = acc.x * sv.x + acc.y * sv.y + acc.z * sv.z + acc.w * sv.w;

#pragma unroll
    for (int off = 32; off > 0; off >>= 1) p += __shfl_down(p, off, 64);
    const int wave = tid >> 6;
    if (lane == 0) sm[wave] = p;
    __syncthreads();
    if (tid == 0) {
        ws[blk] = sm[0] + sm[1] + sm[2];
        // release our partial; acquire everyone else's if we're last
        int old = __hip_atomic_fetch_add(cnt, 1, __ATOMIC_ACQ_REL,
                                         __HIP_MEMORY_SCOPE_AGENT);
        is_last = (old == NBLK - 1);
    }
    __syncthreads();
    if (!is_last) return;

    // ---- finalize (one block, fixed order -> deterministic) ----
    float v = 0.f;
    if (tid < F * B) {                       // threads 0..127, one per fb
        float T = 0.f;
#pragma unroll
        for (int c = 0; c < NCHUNK; ++c) T += ws[tid * NCHUNK + c];
        v = T / (T + EPS);
    }
    if (tid < 128) {
#pragma unroll
        for (int off = 32; off > 0; off >>= 1) v += __shfl_down(v, off, 64);
    }
    __syncthreads();                          // reuse sm[]
    if (tid < 128 && lane == 0) sm[wave] = v;
    __syncthreads();
    if (tid == 0) out[0] = (sm[0] + sm[1]) * (1.0f / (float)F);
}

extern "C" void kernel_launch(void* const* d_in, const int* in_sizes, int n_in,
                              void* d_out, int out_size, void* d_ws, size_t ws_size,
                              hipStream_t stream) {
    const float* tok  = (const float*)d_in[0];
    const float* sent = (const float*)d_in[1];
    const int*   mask = (const int*)d_in[2];
    float* out = (float*)d_out;
    float* ws  = (float*)d_ws;                     // [NBLK] partials
    int*   cnt = (int*)((char*)d_ws + NBLK * 4);   // 4-byte arrival counter

    // d_ws is poisoned once and never re-poisoned between replays: the counter
    // must be zeroed every call (memset node is graph-capturable).
    hipMemsetAsync(cnt, 0, sizeof(int), stream);
    nl_fused<<<NBLK, TPB, 0, stream>>>(tok, sent, mask, ws, cnt, out);
}

// Round 4
// 46.380 us; speedup vs baseline: 3.2130x; 3.2130x over previous
//
#include <hip/hip_runtime.h>

// Problem shape (fixed by reference setup_inputs)
constexpr int F = 2, B = 64, S = 512, D = 768;
constexpr int NCHUNK = 16;            // S-chunks per (f,b)  (R2-proven config)
constexpr int SROWS = S / NCHUNK;     // 32 rows per block
constexpr int TPB = D / 4;            // 192 threads, one float4 column slice each
constexpr int NBLK = F * B * NCHUNK;  // 2048 blocks
constexpr float EPS = 1e-9f;

// Fused single kernel, last-block finalize.
// Cross-block communication (ws partials + arrival counter) uses FINE-GRAINED
// system-scope accesses (sc0/sc1 per-access flags -> memory-side coherence
// point). No ACQ_REL scoped fences: on gfx950 those emit cache-WIDE
// buffer_wbl2/buffer_inv walks per block (R3: 4096 walks = 218 us disaster).
__global__ __launch_bounds__(TPB) void nl_fused(
        const float* __restrict__ tok,   // [F*B, S, D]
        const float* __restrict__ sent,  // [F*B, D]
        const int*   __restrict__ mask,  // [F*B, S]
        float* __restrict__ ws,          // [NBLK] partials
        int*   __restrict__ cnt,         // zeroed by memset node each call
        float* __restrict__ out)
{
    const int blk   = blockIdx.x;            // fb*NCHUNK + chunk
    const int fb    = blk / NCHUNK;
    const int chunk = blk - fb * NCHUNK;
    const int tid   = threadIdx.x;
    const int lane  = tid & 63;

    __shared__ int idxs[SROWS];
    __shared__ int nact;
    __shared__ float sm[TPB / 64];
    __shared__ int is_last;

    const float4 sv = reinterpret_cast<const float4*>(sent + (size_t)fb * D)[tid];

    // active-row list (mask != 0), built by wave 0; uniform across block
    const int* mrow = mask + (size_t)fb * S + chunk * SROWS;
    int mv = 0;
    if (lane < SROWS) mv = mrow[lane];
    unsigned long long bal = __ballot(mv != 0);
    if (tid < 64) {
        if (mv != 0) {
            int pos = __popcll(bal & ((1ull << lane) - 1ull));
            idxs[pos] = lane;
        }
        if (lane == 0) nact = __popcll(bal);
    }
    __syncthreads();
    const int n = nact;

    // dense masked column accumulation (mask=0 rows never fetched)
    const float* tbase = tok + (size_t)fb * S * D + (size_t)chunk * SROWS * D;
    float4 acc = make_float4(0.f, 0.f, 0.f, 0.f);
#pragma unroll 4
    for (int j = 0; j < n; ++j) {
        float4 t = reinterpret_cast<const float4*>(tbase + (size_t)idxs[j] * D)[tid];
        acc.x += t.x; acc.y += t.y; acc.z += t.z; acc.w += t.w;
    }
    float p = acc.x * sv.x + acc.y * sv.y + acc.z * sv.z + acc.w * sv.w;

#pragma unroll
    for (int off = 32; off > 0; off >>= 1) p += __shfl_down(p, off, 64);
    const int wave = tid >> 6;
    if (lane == 0) sm[wave] = p;
    __syncthreads();

    if (tid == 0) {
        float part = sm[0] + sm[1] + sm[2];
        // fine-grained write-through to the coherence point
        __hip_atomic_store(&ws[blk], part, __ATOMIC_RELAXED,
                           __HIP_MEMORY_SCOPE_SYSTEM);
        // ws store must COMPLETE at the coherence point before the arrival tick
        asm volatile("s_waitcnt vmcnt(0)" ::: "memory");
        int old = __hip_atomic_fetch_add(cnt, 1, __ATOMIC_RELAXED,
                                         __HIP_MEMORY_SCOPE_SYSTEM);
        is_last = (old == NBLK - 1);
    }
    __syncthreads();
    if (!is_last) return;

    // ---- finalize by the last-arriving block (fixed order -> deterministic) ----
    float v = 0.f;
    if (tid < F * B) {                       // threads 0..127, one per fb
        float T = 0.f;
#pragma unroll
        for (int c = 0; c < NCHUNK; ++c)
            T += __hip_atomic_load(&ws[tid * NCHUNK + c], __ATOMIC_RELAXED,
                                   __HIP_MEMORY_SCOPE_SYSTEM);
        v = T / (T + EPS);
    }
    if (tid < 128) {
#pragma unroll
        for (int off = 32; off > 0; off >>= 1) v += __shfl_down(v, off, 64);
    }
    __syncthreads();
    if (tid < 128 && lane == 0) sm[wave] = v;
    __syncthreads();
    if (tid == 0) out[0] = (sm[0] + sm[1]) * (1.0f / (float)F);
}

extern "C" void kernel_launch(void* const* d_in, const int* in_sizes, int n_in,
                              void* d_out, int out_size, void* d_ws, size_t ws_size,
                              hipStream_t stream) {
    const float* tok  = (const float*)d_in[0];
    const float* sent = (const float*)d_in[1];
    const int*   mask = (const int*)d_in[2];
    float* out = (float*)d_out;
    float* ws  = (float*)d_ws;                     // [NBLK] partials
    int*   cnt = (int*)((char*)d_ws + NBLK * 4);   // 4-byte arrival counter

    // d_ws poisoned once, never re-poisoned between replays -> zero cnt per call
    hipMemsetAsync(cnt, 0, sizeof(int), stream);
    nl_fused<<<NBLK, TPB, 0, stream>>>(tok, sent, mask, ws, cnt, out);
}

// Round 5
// 23.793 us; speedup vs baseline: 6.2632x; 1.9493x over previous
//
#include <hip/hip_runtime.h>

// Problem shape (fixed by reference setup_inputs)
constexpr int F = 2, B = 64, S = 512, D = 768;
constexpr int NCHUNK = 32;            // S-chunks per (f,b) -> 4096 blocks:
                                      // 2 scheduling rounds/CU absorbs the
                                      // per-CU masked-row-count straggler tail
constexpr int SROWS = S / NCHUNK;     // 16 rows per block
constexpr int TPB = D / 4;            // 192 threads, one float4 column slice each
constexpr float EPS = 1e-9f;

// Phase 1 (R2-proven): per (f,b,chunk) block computes a partial of
// T = sum_s mask[s]*(tok[s,:].sent[:]) via masked column accumulation;
// mask=0 rows are never fetched (halves HBM traffic). No cross-block sync.
__global__ __launch_bounds__(TPB) void nl_partial(
        const float* __restrict__ tok,   // [F*B, S, D]
        const float* __restrict__ sent,  // [F*B, D]
        const int*   __restrict__ mask,  // [F*B, S]
        float* __restrict__ ws)          // [F*B * NCHUNK]
{
    const int blk   = blockIdx.x;            // fb*NCHUNK + chunk
    const int fb    = blk / NCHUNK;
    const int chunk = blk - fb * NCHUNK;
    const int tid   = threadIdx.x;
    const int lane  = tid & 63;

    __shared__ int idxs[SROWS];
    __shared__ int nact;
    __shared__ float sm[TPB / 64];

    const float4 sv = reinterpret_cast<const float4*>(sent + (size_t)fb * D)[tid];

    // active-row list (mask != 0), built by wave 0; uniform across block
    const int* mrow = mask + (size_t)fb * S + chunk * SROWS;
    int mv = 0;
    if (lane < SROWS) mv = mrow[lane];
    unsigned long long bal = __ballot(mv != 0);
    if (tid < 64) {
        if (mv != 0) {
            int pos = __popcll(bal & ((1ull << lane) - 1ull));
            idxs[pos] = lane;
        }
        if (lane == 0) nact = __popcll(bal);
    }
    __syncthreads();
    const int n = nact;

    const float* tbase = tok + (size_t)fb * S * D + (size_t)chunk * SROWS * D;
    float4 acc = make_float4(0.f, 0.f, 0.f, 0.f);
#pragma unroll 4
    for (int j = 0; j < n; ++j) {
        float4 t = reinterpret_cast<const float4*>(tbase + (size_t)idxs[j] * D)[tid];
        acc.x += t.x; acc.y += t.y; acc.z += t.z; acc.w += t.w;
    }
    float p = acc.x * sv.x + acc.y * sv.y + acc.z * sv.z + acc.w * sv.w;

#pragma unroll
    for (int off = 32; off > 0; off >>= 1) p += __shfl_down(p, off, 64);
    const int wave = tid >> 6;
    if (lane == 0) sm[wave] = p;
    __syncthreads();
    if (tid == 0) ws[blk] = sm[0] + sm[1] + sm[2];
}

// Phase 2: one block; thread t owns (f,b)=t, sums its NCHUNK partials,
// applies T/(T+EPS), block-reduces, writes scalar out = sum / F.
__global__ __launch_bounds__(128) void nl_finalize(
        const float* __restrict__ ws, float* __restrict__ out)
{
    const int t = threadIdx.x;               // 128 = F*B threads
    float T = 0.f;
#pragma unroll
    for (int c = 0; c < NCHUNK; ++c) T += ws[t * NCHUNK + c];
    float v = T / (T + EPS);
#pragma unroll
    for (int off = 32; off > 0; off >>= 1) v += __shfl_down(v, off, 64);
    __shared__ float sm[2];
    if ((t & 63) == 0) sm[t >> 6] = v;
    __syncthreads();
    if (t == 0) out[0] = (sm[0] + sm[1]) * (1.0f / (float)F);
}

extern "C" void kernel_launch(void* const* d_in, const int* in_sizes, int n_in,
                              void* d_out, int out_size, void* d_ws, size_t ws_size,
                              hipStream_t stream) {
    const float* tok  = (const float*)d_in[0];
    const float* sent = (const float*)d_in[1];
    const int*   mask = (const int*)d_in[2];
    float* out = (float*)d_out;
    float* ws  = (float*)d_ws;   // needs F*B*NCHUNK*4 = 16 KiB

    nl_partial<<<F * B * NCHUNK, TPB, 0, stream>>>(tok, sent, mask, ws);
    nl_finalize<<<1, 128, 0, stream>>>(ws, out);
}